// Round 2
// baseline (4866.760 us; speedup 1.0000x reference)
//
#include <hip/hip_runtime.h>
#include <math.h>

#define N_NODES 50000
#define N_PAD   50048
#define N_EDGES 640000

__device__ __forceinline__ float silu_f(float x) {
    return x / (1.0f + __expf(-x));
}

// ---------------------------------------------------------------------------
// Edge kernel: one wave (64 threads) per 64-edge tile. Lane e owns edge
// ebase+e. Feature rows staged to LDS [64][65] (transpose buffer; +1 pad ->
// 2-way bank aliasing only, free per m136). Weights read wave-uniform
// (scalarized to s_load by the compiler -> SGPR operand in v_fmac).
// LAYER==1 additionally computes the coord gate (coef) and x_agg scatter.
// All post-GEMV2 consumers read the message from the lane's LDS row instead
// of a live register array (keeps peak VGPR ~1 accumulator).
// ---------------------------------------------------------------------------
template <int LAYER>
__global__ __launch_bounds__(64) void edge_kernel(
    const float* __restrict__ h,    // [N,64]
    const float* __restrict__ x,    // [N,3]
    const float* __restrict__ ef,   // [E,4]
    const int*   __restrict__ src,
    const int*   __restrict__ dst,
    const float* __restrict__ ew1,  // [133,64]
    const float* __restrict__ eb1,  // [64]
    const float* __restrict__ ew2,  // [64,64]
    const float* __restrict__ eb2,  // [64]
    const float* __restrict__ cw1,  // [64,64]
    const float* __restrict__ cb1,  // [64]
    const float* __restrict__ cw2,  // [64]
    float* __restrict__ h_agg,      // [N_PAD,64]
    float* __restrict__ x_agg)      // [N_PAD,3]
{
    __shared__ float fbuf[64 * 65];
    __shared__ int   ridx[64];

    const int lane  = threadIdx.x;         // 0..63
    const int ebase = blockIdx.x * 64;
    const int e     = ebase + lane;

    const int vs = src[e];
    const int vd = dst[e];

    // coords / radial (per-lane, small uncoalesced loads, L2/L3-resident)
    float dx0 = x[vs * 3 + 0] - x[vd * 3 + 0];
    float dx1 = x[vs * 3 + 1] - x[vd * 3 + 1];
    float dx2 = x[vs * 3 + 2] - x[vd * 3 + 2];
    float radial = dx0 * dx0 + dx1 * dx1 + dx2 * dx2;
    float rs = 1.0f / (sqrtf(radial) + 1e-30f);

    const float4 e4 = *reinterpret_cast<const float4*>(ef + (size_t)e * 4);

    // ---------------- GEMV1: f(133) @ ew1(133x64) ----------------
    float acc[64];
#pragma unroll
    for (int j = 0; j < 64; ++j) acc[j] = eb1[j];

    // chunk 0: h[src] columns 0..63
    ridx[lane] = vs;
    __syncthreads();
#pragma unroll 4
    for (int r = 0; r < 64; ++r) {
        fbuf[r * 65 + lane] = h[(size_t)ridx[r] * 64 + lane];
    }
    __syncthreads();
    for (int i = 0; i < 64; ++i) {
        float fi = fbuf[lane * 65 + i];
#pragma unroll
        for (int j = 0; j < 64; ++j) acc[j] += fi * ew1[i * 64 + j];
    }
    __syncthreads();

    // chunk 1: h[dst] columns 64..127
    ridx[lane] = vd;
    __syncthreads();
#pragma unroll 4
    for (int r = 0; r < 64; ++r) {
        fbuf[r * 65 + lane] = h[(size_t)ridx[r] * 64 + lane];
    }
    __syncthreads();
    for (int i = 0; i < 64; ++i) {
        float fi = fbuf[lane * 65 + i];
#pragma unroll
        for (int j = 0; j < 64; ++j) acc[j] += fi * ew1[(64 + i) * 64 + j];
    }

    // tail: radial (col 128), ef (cols 129..132)
#pragma unroll
    for (int j = 0; j < 64; ++j) {
        acc[j] += radial * ew1[128 * 64 + j]
                + e4.x  * ew1[129 * 64 + j]
                + e4.y  * ew1[130 * 64 + j]
                + e4.z  * ew1[131 * 64 + j]
                + e4.w  * ew1[132 * 64 + j];
    }

    // m1 = silu(acc) -> own LDS row (dynamic-index source for GEMV2)
    __syncthreads();
#pragma unroll
    for (int j = 0; j < 64; ++j) fbuf[lane * 65 + j] = silu_f(acc[j]);
    __syncthreads();

    // ---------------- GEMV2: m1 @ ew2(64x64) ----------------
    float acc2[64];
#pragma unroll
    for (int j = 0; j < 64; ++j) acc2[j] = eb2[j];
    for (int i = 0; i < 64; ++i) {
        float fi = fbuf[lane * 65 + i];
#pragma unroll
        for (int j = 0; j < 64; ++j) acc2[j] += fi * ew2[i * 64 + j];
    }

    // m2 = silu(acc2) -> own LDS row; all later consumers read from LDS
    // (avoids a 64-float register array staying live across the gate GEMV)
    __syncthreads();
#pragma unroll
    for (int j = 0; j < 64; ++j) fbuf[lane * 65 + j] = silu_f(acc2[j]);
    __syncthreads();

    // ---------------- coord gate (layer 1 only) ----------------
    if (LAYER == 1) {
        float acc3[64];
#pragma unroll
        for (int j = 0; j < 64; ++j) acc3[j] = cb1[j];
        for (int i = 0; i < 64; ++i) {
            float fi = fbuf[lane * 65 + i];   // m2
#pragma unroll
            for (int j = 0; j < 64; ++j) acc3[j] += fi * cw1[i * 64 + j];
        }
        float coef = 0.0f;
#pragma unroll
        for (int j = 0; j < 64; ++j) coef += silu_f(acc3[j]) * cw2[j];

        atomicAdd(&x_agg[(size_t)vd * 3 + 0], coef * dx0 * rs);
        atomicAdd(&x_agg[(size_t)vd * 3 + 1], coef * dx1 * rs);
        atomicAdd(&x_agg[(size_t)vd * 3 + 2], coef * dx2 * rs);
    }

    // ---------------- h_agg scatter (m2 from LDS) ----------------
    float* hrow = h_agg + (size_t)vd * 64;
#pragma unroll
    for (int j = 0; j < 64; ++j) atomicAdd(hrow + j, fbuf[lane * 65 + j]);
}

// ---------------------------------------------------------------------------
// Node kernel: one wave per 64-node tile. FINAL=0: h1 = relu(node MLP),
// x1 = relu(x + x_agg). FINAL=1: block-reduce node MLP output into d_out.
// ---------------------------------------------------------------------------
template <int FINAL>
__global__ __launch_bounds__(64) void node_kernel(
    const float* __restrict__ h,     // [N,64]
    const float* __restrict__ x,     // [N,3]
    const float* __restrict__ h_agg, // [N_PAD,64]
    const float* __restrict__ x_agg, // [N_PAD,3]
    const float* __restrict__ nw1,   // [128,64]
    const float* __restrict__ nb1,   // [64]
    const float* __restrict__ nw2,   // [64,64]
    const float* __restrict__ nb2,   // [64]
    float* __restrict__ h_out,       // FINAL=0: [N_PAD,64]; FINAL=1: [64]
    float* __restrict__ x_out)       // FINAL=0: [N_PAD,3]
{
    __shared__ float fbuf[64 * 65];

    const int lane  = threadIdx.x;
    const int nbase = blockIdx.x * 64;
    const int node  = nbase + lane;
    const bool valid = node < N_NODES;

    float acc[64];
#pragma unroll
    for (int j = 0; j < 64; ++j) acc[j] = nb1[j];

    // chunk 0: h rows (contiguous; clamp OOB rows)
#pragma unroll 4
    for (int r = 0; r < 64; ++r) {
        int rr = nbase + r; rr = rr < N_NODES ? rr : (N_NODES - 1);
        fbuf[r * 65 + lane] = h[(size_t)rr * 64 + lane];
    }
    __syncthreads();
    for (int i = 0; i < 64; ++i) {
        float fi = fbuf[lane * 65 + i];
#pragma unroll
        for (int j = 0; j < 64; ++j) acc[j] += fi * nw1[i * 64 + j];
    }
    __syncthreads();

    // chunk 1: h_agg rows (padded allocation, always in-bounds)
#pragma unroll 4
    for (int r = 0; r < 64; ++r) {
        fbuf[r * 65 + lane] = h_agg[(size_t)(nbase + r) * 64 + lane];
    }
    __syncthreads();
    for (int i = 0; i < 64; ++i) {
        float fi = fbuf[lane * 65 + i];
#pragma unroll
        for (int j = 0; j < 64; ++j) acc[j] += fi * nw1[(64 + i) * 64 + j];
    }
    __syncthreads();

    // silu -> own LDS row
#pragma unroll
    for (int j = 0; j < 64; ++j) fbuf[lane * 65 + j] = silu_f(acc[j]);
    __syncthreads();

    float acc2[64];
#pragma unroll
    for (int j = 0; j < 64; ++j) acc2[j] = nb2[j];
    for (int i = 0; i < 64; ++i) {
        float fi = fbuf[lane * 65 + i];
#pragma unroll
        for (int j = 0; j < 64; ++j) acc2[j] += fi * nw2[i * 64 + j];
    }

    if (FINAL == 0) {
        if (valid) {
#pragma unroll
            for (int j = 0; j < 64; ++j)
                h_out[(size_t)node * 64 + j] = fmaxf(acc2[j], 0.0f);
#pragma unroll
            for (int k = 0; k < 3; ++k)
                x_out[(size_t)node * 3 + k] =
                    fmaxf(x[(size_t)node * 3 + k] + x_agg[(size_t)node * 3 + k], 0.0f);
        }
    } else {
        __syncthreads();
#pragma unroll
        for (int j = 0; j < 64; ++j) fbuf[lane * 65 + j] = valid ? acc2[j] : 0.0f;
        __syncthreads();
        float s = 0.0f;
        for (int r = 0; r < 64; ++r) s += fbuf[r * 65 + lane];
        atomicAdd(&h_out[lane], s);
    }
}

extern "C" void kernel_launch(void* const* d_in, const int* in_sizes, int n_in,
                              void* d_out, int out_size, void* d_ws, size_t ws_size,
                              hipStream_t stream) {
    const float* node_feat = (const float*)d_in[0];
    const float* coord     = (const float*)d_in[1];
    const float* edge_feat = (const float*)d_in[2];
    const int*   src       = (const int*)d_in[3];
    const int*   dst       = (const int*)d_in[4];

    const float* p1[11];
    const float* p2[11];
    for (int i = 0; i < 11; ++i) p1[i] = (const float*)d_in[5 + i];
    for (int i = 0; i < 11; ++i) p2[i] = (const float*)d_in[16 + i];
    // order: ew1 eb1 ew2 eb2 cw1 cb1 cw2 nw1 nb1 nw2 nb2

    float* out = (float*)d_out;

    float* h_agg = (float*)d_ws;                       // N_PAD*64
    float* x_agg = h_agg + (size_t)N_PAD * 64;         // N_PAD*3
    float* h1    = x_agg + (size_t)N_PAD * 3;          // N_PAD*64
    float* x1    = h1    + (size_t)N_PAD * 64;         // N_PAD*3

    hipMemsetAsync(h_agg, 0, (size_t)N_PAD * 64 * sizeof(float), stream);
    hipMemsetAsync(x_agg, 0, (size_t)N_PAD * 3 * sizeof(float), stream);
    hipMemsetAsync(out,   0, 64 * sizeof(float), stream);

    // ---- layer 1 ----
    edge_kernel<1><<<N_EDGES / 64, 64, 0, stream>>>(
        node_feat, coord, edge_feat, src, dst,
        p1[0], p1[1], p1[2], p1[3], p1[4], p1[5], p1[6],
        h_agg, x_agg);
    node_kernel<0><<<(N_NODES + 63) / 64, 64, 0, stream>>>(
        node_feat, coord, h_agg, x_agg,
        p1[7], p1[8], p1[9], p1[10],
        h1, x1);

    // ---- layer 2 ----
    hipMemsetAsync(h_agg, 0, (size_t)N_PAD * 64 * sizeof(float), stream);
    edge_kernel<2><<<N_EDGES / 64, 64, 0, stream>>>(
        h1, x1, edge_feat, src, dst,
        p2[0], p2[1], p2[2], p2[3], p2[4], p2[5], p2[6],
        h_agg, x_agg);
    node_kernel<1><<<(N_NODES + 63) / 64, 64, 0, stream>>>(
        h1, x1, h_agg, x_agg,
        p2[7], p2[8], p2[9], p2[10],
        out, nullptr);
}

// Round 9
// 1140.224 us; speedup vs baseline: 4.2682x; 4.2682x over previous
//
#include <hip/hip_runtime.h>
#include <math.h>

#define N_NODES 50000
#define N_PAD   50048
#define N_EDGES 640000

__device__ __forceinline__ float silu_f(float x) {
    return x / (1.0f + __expf(-x));
}

// ---------------------------------------------------------------------------
// CSR build: count -> exclusive scan (1 block) -> fill
// ---------------------------------------------------------------------------
__global__ __launch_bounds__(256) void count_kernel(const int* __restrict__ dst,
                                                    int* __restrict__ cnt) {
    int e = blockIdx.x * 256 + threadIdx.x;
    if (e < N_EDGES) atomicAdd(&cnt[dst[e]], 1);
}

__global__ __launch_bounds__(1024) void scan_kernel(const int* __restrict__ cnt,
                                                    int* __restrict__ starts,
                                                    int* __restrict__ wcur) {
    __shared__ int sbase[1024];
    const int t = threadIdx.x;
    const int CH = (N_NODES + 1023) / 1024;           // 49
    int lo = t * CH;
    int hi = lo + CH; if (hi > N_NODES) hi = N_NODES;
    int s = 0;
    for (int i = lo; i < hi; ++i) s += cnt[i];
    sbase[t] = s;
    __syncthreads();
    for (int d = 1; d < 1024; d <<= 1) {              // Hillis-Steele inclusive
        int v = sbase[t];
        int add = (t >= d) ? sbase[t - d] : 0;
        __syncthreads();
        sbase[t] = v + add;
        __syncthreads();
    }
    int run = (t == 0) ? 0 : sbase[t - 1];            // exclusive prefix
    for (int i = lo; i < hi; ++i) {
        starts[i] = run;
        wcur[i]   = run;
        run += cnt[i];
    }
}

__global__ __launch_bounds__(256) void fill_kernel(const int* __restrict__ dst,
                                                   int* __restrict__ wcur,
                                                   int* __restrict__ eids) {
    int e = blockIdx.x * 256 + threadIdx.x;
    if (e < N_EDGES) {
        int p = atomicAdd(&wcur[dst[e]], 1);
        eids[p] = e;
    }
}

// ---------------------------------------------------------------------------
// Edge kernel: 256 threads = 4 waves per 64-edge tile. lane = edge-in-tile,
// wave wv owns output columns [J0, J0+16). J0 is pinned to an SGPR via
// readfirstlane so weight/bias addresses are provably wave-uniform ->
// s_load + SGPR-operand v_fmac (hipcc can't prove tid>>6 uniform itself).
// CSR=1: stream m2 to msg[E,64] (coalesced), coef*dx to cx[E,3].
// CSR=0: legacy atomicAdd scatter (fallback when ws too small).
// ---------------------------------------------------------------------------
template <int LAYER, int CSR>
__global__ __launch_bounds__(256) void edge_kernel(
    const float* __restrict__ h,    // [N,64]
    const float* __restrict__ x,    // [N,3]
    const float* __restrict__ ef,   // [E,4]
    const int*   __restrict__ src,
    const int*   __restrict__ dst,
    const float* __restrict__ ew1,  // [133,64]
    const float* __restrict__ eb1,
    const float* __restrict__ ew2,  // [64,64]
    const float* __restrict__ eb2,
    const float* __restrict__ cw1,  // [64,64]
    const float* __restrict__ cb1,
    const float* __restrict__ cw2,  // [64]
    float* __restrict__ msg,        // CSR: [E,64]
    float* __restrict__ cx,         // CSR, layer1: [E,3]
    float* __restrict__ h_agg,      // fallback: [N_PAD,64]
    float* __restrict__ x_agg)      // fallback: [N_PAD,3]
{
    __shared__ float fbuf[64 * 65];
    __shared__ int   ridx[64];
    __shared__ float gbuf[256];

    const int tid   = threadIdx.x;
    const int lane  = tid & 63;
    const int wv    = tid >> 6;
    const int J0    = __builtin_amdgcn_readfirstlane(wv * 16);  // SGPR slice base
    const int ebase = blockIdx.x * 64;
    const int e     = ebase + lane;

    const int vs = src[e];
    const int vd = dst[e];

    float dx0 = x[vs * 3 + 0] - x[vd * 3 + 0];
    float dx1 = x[vs * 3 + 1] - x[vd * 3 + 1];
    float dx2 = x[vs * 3 + 2] - x[vd * 3 + 2];
    float radial = dx0 * dx0 + dx1 * dx1 + dx2 * dx2;
    float rs = 1.0f / (sqrtf(radial) + 1e-30f);

    const float4 e4 = *reinterpret_cast<const float4*>(ef + (size_t)e * 4);

    // ---------------- GEMV1: f(133) @ ew1 ----------------
    float acc[16];
#pragma unroll
    for (int jj = 0; jj < 16; ++jj) acc[jj] = eb1[J0 + jj];

    // chunk 0: h[src]
    if (wv == 0) ridx[lane] = vs;
    __syncthreads();
#pragma unroll
    for (int rr = 0; rr < 16; ++rr) {
        int r = wv * 16 + rr;
        fbuf[r * 65 + lane] = h[(size_t)ridx[r] * 64 + lane];
    }
    __syncthreads();
    for (int i = 0; i < 64; ++i) {
        float fi = fbuf[lane * 65 + i];
#pragma unroll
        for (int jj = 0; jj < 16; ++jj) acc[jj] += fi * ew1[i * 64 + J0 + jj];
    }
    __syncthreads();

    // chunk 1: h[dst]
    if (wv == 0) ridx[lane] = vd;
    __syncthreads();
#pragma unroll
    for (int rr = 0; rr < 16; ++rr) {
        int r = wv * 16 + rr;
        fbuf[r * 65 + lane] = h[(size_t)ridx[r] * 64 + lane];
    }
    __syncthreads();
    for (int i = 0; i < 64; ++i) {
        float fi = fbuf[lane * 65 + i];
#pragma unroll
        for (int jj = 0; jj < 16; ++jj) acc[jj] += fi * ew1[(64 + i) * 64 + J0 + jj];
    }

    // tail: radial + ef
#pragma unroll
    for (int jj = 0; jj < 16; ++jj) {
        int j = J0 + jj;
        acc[jj] += radial * ew1[128 * 64 + j]
                 + e4.x  * ew1[129 * 64 + j]
                 + e4.y  * ew1[130 * 64 + j]
                 + e4.z  * ew1[131 * 64 + j]
                 + e4.w  * ew1[132 * 64 + j];
    }

    // m1 -> fbuf
    __syncthreads();
#pragma unroll
    for (int jj = 0; jj < 16; ++jj) fbuf[lane * 65 + J0 + jj] = silu_f(acc[jj]);
    __syncthreads();

    // ---------------- GEMV2 ----------------
    float acc2[16];
#pragma unroll
    for (int jj = 0; jj < 16; ++jj) acc2[jj] = eb2[J0 + jj];
    for (int i = 0; i < 64; ++i) {
        float fi = fbuf[lane * 65 + i];
#pragma unroll
        for (int jj = 0; jj < 16; ++jj) acc2[jj] += fi * ew2[i * 64 + J0 + jj];
    }
    __syncthreads();
#pragma unroll
    for (int jj = 0; jj < 16; ++jj) fbuf[lane * 65 + J0 + jj] = silu_f(acc2[jj]);
    __syncthreads();   // fbuf now holds m2 for all 64 edges

    // ---------------- coord gate (layer 1) ----------------
    if (LAYER == 1) {
        float acc3[16];
#pragma unroll
        for (int jj = 0; jj < 16; ++jj) acc3[jj] = cb1[J0 + jj];
        for (int i = 0; i < 64; ++i) {
            float fi = fbuf[lane * 65 + i];
#pragma unroll
            for (int jj = 0; jj < 16; ++jj) acc3[jj] += fi * cw1[i * 64 + J0 + jj];
        }
        float part = 0.0f;
#pragma unroll
        for (int jj = 0; jj < 16; ++jj) part += silu_f(acc3[jj]) * cw2[J0 + jj];
        gbuf[wv * 64 + lane] = part;
        __syncthreads();
        if (wv == 0) {
            float coef = gbuf[lane] + gbuf[64 + lane] + gbuf[128 + lane] + gbuf[192 + lane];
            if (CSR) {
                cx[(size_t)e * 3 + 0] = coef * dx0 * rs;
                cx[(size_t)e * 3 + 1] = coef * dx1 * rs;
                cx[(size_t)e * 3 + 2] = coef * dx2 * rs;
            } else {
                atomicAdd(&x_agg[(size_t)vd * 3 + 0], coef * dx0 * rs);
                atomicAdd(&x_agg[(size_t)vd * 3 + 1], coef * dx1 * rs);
                atomicAdd(&x_agg[(size_t)vd * 3 + 2], coef * dx2 * rs);
            }
        }
    }

    // ---------------- emit m2 ----------------
    if (CSR) {
#pragma unroll
        for (int rr = 0; rr < 16; ++rr) {
            int r = wv * 16 + rr;
            msg[(size_t)(ebase + r) * 64 + lane] = fbuf[r * 65 + lane];
        }
    } else {
        float* hrow = h_agg + (size_t)vd * 64;
#pragma unroll
        for (int jj = 0; jj < 16; ++jj)
            atomicAdd(hrow + J0 + jj, fbuf[lane * 65 + J0 + jj]);
    }
}

// ---------------------------------------------------------------------------
// Aggregation: one wave per node, lane = feature. Coalesced 256B row reads.
// ---------------------------------------------------------------------------
template <int LAYER>
__global__ __launch_bounds__(256) void agg_kernel(
    const float* __restrict__ msg,     // [E,64]
    const float* __restrict__ cx,      // [E,3]
    const int*   __restrict__ eids,
    const int*   __restrict__ starts,
    const int*   __restrict__ cnt,
    float* __restrict__ h_agg,         // [N_PAD,64]
    float* __restrict__ x_agg)         // [N_PAD,3]
{
    const int lane = threadIdx.x & 63;
    const int wv   = threadIdx.x >> 6;
    const int node = blockIdx.x * 4 + wv;

    float a  = 0.0f;
    float xa = 0.0f;
    if (node < N_NODES) {
        int s = starts[node];
        int d = cnt[node];
        for (int k = 0; k < d; ++k) {
            int eid = eids[s + k];
            a += msg[(size_t)eid * 64 + lane];
            if (LAYER == 1 && lane < 3) xa += cx[(size_t)eid * 3 + lane];
        }
    }
    h_agg[(size_t)node * 64 + lane] = a;
    if (LAYER == 1 && lane < 3) x_agg[(size_t)node * 3 + lane] = xa;
}

// ---------------------------------------------------------------------------
// Node kernel: one wave per 64-node tile. FINAL=0: h1 = relu(node MLP),
// x1 = relu(x + x_agg). FINAL=1: block-reduce node MLP output into d_out.
// ---------------------------------------------------------------------------
template <int FINAL>
__global__ __launch_bounds__(64) void node_kernel(
    const float* __restrict__ h,
    const float* __restrict__ x,
    const float* __restrict__ h_agg,
    const float* __restrict__ x_agg,
    const float* __restrict__ nw1,
    const float* __restrict__ nb1,
    const float* __restrict__ nw2,
    const float* __restrict__ nb2,
    float* __restrict__ h_out,
    float* __restrict__ x_out)
{
    __shared__ float fbuf[64 * 65];

    const int lane  = threadIdx.x;
    const int nbase = blockIdx.x * 64;
    const int node  = nbase + lane;
    const bool valid = node < N_NODES;

    float acc[64];
#pragma unroll
    for (int j = 0; j < 64; ++j) acc[j] = nb1[j];

#pragma unroll 4
    for (int r = 0; r < 64; ++r) {
        int rr = nbase + r; rr = rr < N_NODES ? rr : (N_NODES - 1);
        fbuf[r * 65 + lane] = h[(size_t)rr * 64 + lane];
    }
    __syncthreads();
    for (int i = 0; i < 64; ++i) {
        float fi = fbuf[lane * 65 + i];
#pragma unroll
        for (int j = 0; j < 64; ++j) acc[j] += fi * nw1[i * 64 + j];
    }
    __syncthreads();

#pragma unroll 4
    for (int r = 0; r < 64; ++r) {
        fbuf[r * 65 + lane] = h_agg[(size_t)(nbase + r) * 64 + lane];
    }
    __syncthreads();
    for (int i = 0; i < 64; ++i) {
        float fi = fbuf[lane * 65 + i];
#pragma unroll
        for (int j = 0; j < 64; ++j) acc[j] += fi * nw1[(64 + i) * 64 + j];
    }
    __syncthreads();

#pragma unroll
    for (int j = 0; j < 64; ++j) fbuf[lane * 65 + j] = silu_f(acc[j]);
    __syncthreads();

    float acc2[64];
#pragma unroll
    for (int j = 0; j < 64; ++j) acc2[j] = nb2[j];
    for (int i = 0; i < 64; ++i) {
        float fi = fbuf[lane * 65 + i];
#pragma unroll
        for (int j = 0; j < 64; ++j) acc2[j] += fi * nw2[i * 64 + j];
    }

    if (FINAL == 0) {
        if (valid) {
#pragma unroll
            for (int j = 0; j < 64; ++j)
                h_out[(size_t)node * 64 + j] = fmaxf(acc2[j], 0.0f);
#pragma unroll
            for (int k = 0; k < 3; ++k)
                x_out[(size_t)node * 3 + k] =
                    fmaxf(x[(size_t)node * 3 + k] + x_agg[(size_t)node * 3 + k], 0.0f);
        }
    } else {
        __syncthreads();
#pragma unroll
        for (int j = 0; j < 64; ++j) fbuf[lane * 65 + j] = valid ? acc2[j] : 0.0f;
        __syncthreads();
        float s = 0.0f;
        for (int r = 0; r < 64; ++r) s += fbuf[r * 65 + lane];
        atomicAdd(&h_out[lane], s);
    }
}

extern "C" void kernel_launch(void* const* d_in, const int* in_sizes, int n_in,
                              void* d_out, int out_size, void* d_ws, size_t ws_size,
                              hipStream_t stream) {
    const float* node_feat = (const float*)d_in[0];
    const float* coord     = (const float*)d_in[1];
    const float* edge_feat = (const float*)d_in[2];
    const int*   src       = (const int*)d_in[3];
    const int*   dst       = (const int*)d_in[4];

    const float* p1[11];
    const float* p2[11];
    for (int i = 0; i < 11; ++i) p1[i] = (const float*)d_in[5 + i];
    for (int i = 0; i < 11; ++i) p2[i] = (const float*)d_in[16 + i];
    // order: ew1 eb1 ew2 eb2 cw1 cb1 cw2 nw1 nb1 nw2 nb2

    float* out = (float*)d_out;

    // workspace layout (floats, then ints)
    float* fw    = (float*)d_ws;
    size_t off   = 0;
    float* h_agg = fw + off; off += (size_t)N_PAD * 64;
    float* x_agg = fw + off; off += (size_t)N_PAD * 3;
    float* h1    = fw + off; off += (size_t)N_PAD * 64;
    float* x1    = fw + off; off += (size_t)N_PAD * 3;
    float* msg   = fw + off; off += (size_t)N_EDGES * 64;
    float* cx    = fw + off; off += (size_t)N_EDGES * 3;
    int*   iw    = (int*)(fw + off);
    int*   eids   = iw;
    int*   cnt    = iw + N_EDGES;
    int*   starts = cnt + N_NODES;
    int*   wcur   = starts + N_NODES;
    size_t need_bytes = off * sizeof(float) + (size_t)(N_EDGES + 3 * N_NODES) * sizeof(int);

    const bool use_csr = ws_size >= need_bytes;

    hipMemsetAsync(out, 0, 64 * sizeof(float), stream);

    if (use_csr) {
        // ---- build CSR by dst (once; shared by both layers) ----
        hipMemsetAsync(cnt, 0, (size_t)N_NODES * sizeof(int), stream);
        count_kernel<<<(N_EDGES + 255) / 256, 256, 0, stream>>>(dst, cnt);
        scan_kernel<<<1, 1024, 0, stream>>>(cnt, starts, wcur);
        fill_kernel<<<(N_EDGES + 255) / 256, 256, 0, stream>>>(dst, wcur, eids);

        // ---- layer 1 ----
        edge_kernel<1, 1><<<N_EDGES / 64, 256, 0, stream>>>(
            node_feat, coord, edge_feat, src, dst,
            p1[0], p1[1], p1[2], p1[3], p1[4], p1[5], p1[6],
            msg, cx, nullptr, nullptr);
        agg_kernel<1><<<N_PAD / 4, 256, 0, stream>>>(
            msg, cx, eids, starts, cnt, h_agg, x_agg);
        node_kernel<0><<<(N_NODES + 63) / 64, 64, 0, stream>>>(
            node_feat, coord, h_agg, x_agg,
            p1[7], p1[8], p1[9], p1[10], h1, x1);

        // ---- layer 2 ----
        edge_kernel<2, 1><<<N_EDGES / 64, 256, 0, stream>>>(
            h1, x1, edge_feat, src, dst,
            p2[0], p2[1], p2[2], p2[3], p2[4], p2[5], p2[6],
            msg, cx, nullptr, nullptr);
        agg_kernel<2><<<N_PAD / 4, 256, 0, stream>>>(
            msg, cx, eids, starts, cnt, h_agg, x_agg);
        node_kernel<1><<<(N_NODES + 63) / 64, 64, 0, stream>>>(
            h1, x1, h_agg, x_agg,
            p2[7], p2[8], p2[9], p2[10], out, nullptr);
    } else {
        // ---- fallback: atomic scatter path ----
        hipMemsetAsync(h_agg, 0, (size_t)N_PAD * 64 * sizeof(float), stream);
        hipMemsetAsync(x_agg, 0, (size_t)N_PAD * 3 * sizeof(float), stream);

        edge_kernel<1, 0><<<N_EDGES / 64, 256, 0, stream>>>(
            node_feat, coord, edge_feat, src, dst,
            p1[0], p1[1], p1[2], p1[3], p1[4], p1[5], p1[6],
            nullptr, nullptr, h_agg, x_agg);
        node_kernel<0><<<(N_NODES + 63) / 64, 64, 0, stream>>>(
            node_feat, coord, h_agg, x_agg,
            p1[7], p1[8], p1[9], p1[10], h1, x1);

        hipMemsetAsync(h_agg, 0, (size_t)N_PAD * 64 * sizeof(float), stream);
        edge_kernel<2, 0><<<N_EDGES / 64, 256, 0, stream>>>(
            h1, x1, edge_feat, src, dst,
            p2[0], p2[1], p2[2], p2[3], p2[4], p2[5], p2[6],
            nullptr, nullptr, h_agg, x_agg);
        node_kernel<1><<<(N_NODES + 63) / 64, 64, 0, stream>>>(
            h1, x1, h_agg, x_agg,
            p2[7], p2[8], p2[9], p2[10], out, nullptr);
    }
}

// Round 15
// 887.603 us; speedup vs baseline: 5.4830x; 1.2846x over previous
//
#include <hip/hip_runtime.h>
#include <math.h>

#define N_NODES 50000
#define N_PAD   50048
#define N_EDGES 640000

typedef __attribute__((ext_vector_type(8))) short short8v;
typedef __attribute__((ext_vector_type(4))) float f32x4;

__device__ __forceinline__ float silu_f(float x) {
    return x / (1.0f + __expf(-x));
}

__device__ __forceinline__ unsigned short f2b(float f) {   // fp32 -> bf16 RNE
    union { float f; unsigned u; } v; v.f = f;
    unsigned r = v.u + 0x7fffu + ((v.u >> 16) & 1u);
    return (unsigned short)(r >> 16);
}

// ---------------------------------------------------------------------------
// CSR build: count -> exclusive scan (1 block) -> fill
// ---------------------------------------------------------------------------
__global__ __launch_bounds__(256) void count_kernel(const int* __restrict__ dst,
                                                    int* __restrict__ cnt) {
    int e = blockIdx.x * 256 + threadIdx.x;
    if (e < N_EDGES) atomicAdd(&cnt[dst[e]], 1);
}

__global__ __launch_bounds__(1024) void scan_kernel(const int* __restrict__ cnt,
                                                    int* __restrict__ starts,
                                                    int* __restrict__ wcur) {
    __shared__ int sbase[1024];
    const int t = threadIdx.x;
    const int CH = (N_NODES + 1023) / 1024;
    int lo = t * CH;
    int hi = lo + CH; if (hi > N_NODES) hi = N_NODES;
    int s = 0;
    for (int i = lo; i < hi; ++i) s += cnt[i];
    sbase[t] = s;
    __syncthreads();
    for (int d = 1; d < 1024; d <<= 1) {
        int v = sbase[t];
        int add = (t >= d) ? sbase[t - d] : 0;
        __syncthreads();
        sbase[t] = v + add;
        __syncthreads();
    }
    int run = (t == 0) ? 0 : sbase[t - 1];
    for (int i = lo; i < hi; ++i) {
        starts[i] = run;
        wcur[i]   = run;
        run += cnt[i];
    }
}

__global__ __launch_bounds__(256) void fill_kernel(const int* __restrict__ dst,
                                                   int* __restrict__ wcur,
                                                   int* __restrict__ eids) {
    int e = blockIdx.x * 256 + threadIdx.x;
    if (e < N_EDGES) {
        int p = atomicAdd(&wcur[dst[e]], 1);
        eids[p] = e;
    }
}

// ---------------------------------------------------------------------------
// Weight prep: transpose + pad + bf16-convert edge-MLP weights.
// wt1[n][160] (K padded 133->160, zeros), wt2[n][64], wtc[n][64].
// ---------------------------------------------------------------------------
__global__ __launch_bounds__(256) void prep_weights(
    const float* __restrict__ ew1_1, const float* __restrict__ ew2_1,
    const float* __restrict__ cw1_1,
    const float* __restrict__ ew1_2, const float* __restrict__ ew2_2,
    unsigned short* __restrict__ wt1_1, unsigned short* __restrict__ wt2_1,
    unsigned short* __restrict__ wtc_1,
    unsigned short* __restrict__ wt1_2, unsigned short* __restrict__ wt2_2)
{
    int idx = blockIdx.x * 256 + threadIdx.x;
    if (idx < 64 * 160) {
        int n = idx / 160, k = idx % 160;
        float a = (k < 133) ? ew1_1[k * 64 + n] : 0.0f;
        float b = (k < 133) ? ew1_2[k * 64 + n] : 0.0f;
        wt1_1[idx] = f2b(a);
        wt1_2[idx] = f2b(b);
    } else if (idx < 64 * 160 + 64 * 64) {
        int j = idx - 64 * 160;
        int n = j / 64, k = j % 64;
        wt2_1[j] = f2b(ew2_1[k * 64 + n]);
        wt2_2[j] = f2b(ew2_2[k * 64 + n]);
        wtc_1[j] = f2b(cw1_1[k * 64 + n]);
    }
}

// ---------------------------------------------------------------------------
// MFMA edge kernel: 256 threads = 4 waves per 64-edge tile. Wave wv owns
// edge rows [wv*16, wv*16+16) end-to-end (GEMM1 -> GEMM2 -> gate), so the
// compute phase needs no block barriers. f-matrix staged bf16 in LDS
// [64][168] (stride 336B -> 2-way-conflict b128 A-reads); m1/m2 at stride
// 72 (144B, 2-way). B-fragments are 16B contiguous loads from pre-
// transposed bf16 weights (L1-hot, identical across blocks). K-mapping of
// A and B fragments uses the same (lane/16,elem) function, so the MFMA dot
// product is correct under any HW k-permutation; C layout per m89.
// ---------------------------------------------------------------------------
template <int LAYER>
__global__ __launch_bounds__(256) void edge_mfma_kernel(
    const float* __restrict__ h,     // [N,64]
    const float* __restrict__ x,     // [N,3]
    const float* __restrict__ ef,    // [E,4]
    const int*   __restrict__ src,
    const int*   __restrict__ dst,
    const unsigned short* __restrict__ wt1,  // [64][160] bf16 (n-major)
    const float* __restrict__ eb1,
    const unsigned short* __restrict__ wt2,  // [64][64]
    const float* __restrict__ eb2,
    const unsigned short* __restrict__ wtc,  // [64][64] (layer1)
    const float* __restrict__ cb1,
    const float* __restrict__ cw2,
    float* __restrict__ msg,         // [E,64]
    float* __restrict__ cx)          // [E,3] (layer1)
{
    __shared__ unsigned short fbuf[64 * 168];   // 21504 B
    __shared__ unsigned short m1buf[64 * 72];   //  9216 B
    __shared__ unsigned short m2buf[64 * 72];   //  9216 B
    __shared__ int   sbuf[64], dbuf[64];
    __shared__ float wcoef[64];

    const int tid   = threadIdx.x;
    const int lane  = tid & 63;
    const int wv    = tid >> 6;
    const int c     = lane & 15;       // fragment col / A-row-in-tile
    const int q     = lane >> 4;       // quarter -> k offset q*8
    const int row0  = wv * 16;         // wave's edge-row base (block-local)
    const int ebase = blockIdx.x * 64;

    if (tid < 64) {
        int e = ebase + tid;
        sbuf[tid] = src[e];
        dbuf[tid] = dst[e];
    }
    __syncthreads();

    // per-edge scalars: lanes 0..15 of each wave own row row0+lane
    float dx0 = 0.f, dx1 = 0.f, dx2 = 0.f, rs = 0.f;
    if (lane < 16) {
        int r = row0 + lane;
        int e = ebase + r;
        int vs = sbuf[r], vd = dbuf[r];
        dx0 = x[vs * 3 + 0] - x[vd * 3 + 0];
        dx1 = x[vs * 3 + 1] - x[vd * 3 + 1];
        dx2 = x[vs * 3 + 2] - x[vd * 3 + 2];
        float radial = dx0 * dx0 + dx1 * dx1 + dx2 * dx2;
        rs = 1.0f / (sqrtf(radial) + 1e-30f);
        const float4 e4 = *reinterpret_cast<const float4*>(ef + (size_t)e * 4);
        unsigned short* frow = &fbuf[r * 168];
        frow[128] = f2b(radial);
        frow[129] = f2b(e4.x);
        frow[130] = f2b(e4.y);
        frow[131] = f2b(e4.z);
        frow[132] = f2b(e4.w);
#pragma unroll
        for (int cc = 133; cc < 160; ++cc) frow[cc] = 0;
    }

    // gather h[src],h[dst] for the wave's 16 rows (all 64 lanes, coalesced)
    for (int rr = 0; rr < 16; ++rr) {
        int r = row0 + rr;
        fbuf[r * 168 + lane]      = f2b(h[(size_t)sbuf[r] * 64 + lane]);
        fbuf[r * 168 + 64 + lane] = f2b(h[(size_t)dbuf[r] * 64 + lane]);
    }
    __syncthreads();

    const int arow = row0 + c;   // this lane's A row (block-local edge index)

    // ---------------- GEMM1: f[64x160] @ wt1 -> m1 ----------------
#pragma unroll
    for (int cg = 0; cg < 4; ++cg) {
        f32x4 acc = {0.f, 0.f, 0.f, 0.f};
#pragma unroll
        for (int ks = 0; ks < 5; ++ks) {
            short8v av = *reinterpret_cast<const short8v*>(
                &fbuf[arow * 168 + ks * 32 + q * 8]);
            short8v bv = *reinterpret_cast<const short8v*>(
                &wt1[(size_t)(c + 16 * cg) * 160 + ks * 32 + q * 8]);
            acc = __builtin_amdgcn_mfma_f32_16x16x32_bf16(av, bv, acc, 0, 0, 0);
        }
        float bias = eb1[c + 16 * cg];
#pragma unroll
        for (int i = 0; i < 4; ++i) {
            float v = silu_f(acc[i] + bias);
            m1buf[(row0 + q * 4 + i) * 72 + c + 16 * cg] = f2b(v);
        }
    }

    // ---------------- GEMM2: m1[64x64] @ wt2 -> m2 ----------------
#pragma unroll
    for (int cg = 0; cg < 4; ++cg) {
        f32x4 acc = {0.f, 0.f, 0.f, 0.f};
#pragma unroll
        for (int ks = 0; ks < 2; ++ks) {
            short8v av = *reinterpret_cast<const short8v*>(
                &m1buf[arow * 72 + ks * 32 + q * 8]);
            short8v bv = *reinterpret_cast<const short8v*>(
                &wt2[(size_t)(c + 16 * cg) * 64 + ks * 32 + q * 8]);
            acc = __builtin_amdgcn_mfma_f32_16x16x32_bf16(av, bv, acc, 0, 0, 0);
        }
        float bias = eb2[c + 16 * cg];
#pragma unroll
        for (int i = 0; i < 4; ++i) {
            float v = silu_f(acc[i] + bias);
            int r = row0 + q * 4 + i;
            msg[(size_t)(ebase + r) * 64 + c + 16 * cg] = v;
            if (LAYER == 1) m2buf[r * 72 + c + 16 * cg] = f2b(v);
        }
    }

    // ---------------- coord gate (layer 1) ----------------
    if (LAYER == 1) {
        float part0 = 0.f, part1 = 0.f, part2 = 0.f, part3 = 0.f;
#pragma unroll
        for (int cg = 0; cg < 4; ++cg) {
            f32x4 acc = {0.f, 0.f, 0.f, 0.f};
#pragma unroll
            for (int ks = 0; ks < 2; ++ks) {
                short8v av = *reinterpret_cast<const short8v*>(
                    &m2buf[arow * 72 + ks * 32 + q * 8]);
                short8v bv = *reinterpret_cast<const short8v*>(
                    &wtc[(size_t)(c + 16 * cg) * 64 + ks * 32 + q * 8]);
                acc = __builtin_amdgcn_mfma_f32_16x16x32_bf16(av, bv, acc, 0, 0, 0);
            }
            float bias = cb1[c + 16 * cg];
            float w2   = cw2[c + 16 * cg];
            part0 += silu_f(acc[0] + bias) * w2;
            part1 += silu_f(acc[1] + bias) * w2;
            part2 += silu_f(acc[2] + bias) * w2;
            part3 += silu_f(acc[3] + bias) * w2;
        }
#pragma unroll
        for (int m = 1; m < 16; m <<= 1) {
            part0 += __shfl_xor(part0, m, 64);
            part1 += __shfl_xor(part1, m, 64);
            part2 += __shfl_xor(part2, m, 64);
            part3 += __shfl_xor(part3, m, 64);
        }
        if (c == 0) {
            wcoef[row0 + q * 4 + 0] = part0;
            wcoef[row0 + q * 4 + 1] = part1;
            wcoef[row0 + q * 4 + 2] = part2;
            wcoef[row0 + q * 4 + 3] = part3;
        }
        __syncthreads();
        if (lane < 16) {
            float coef = wcoef[row0 + lane];
            int e = ebase + row0 + lane;
            cx[(size_t)e * 3 + 0] = coef * dx0 * rs;
            cx[(size_t)e * 3 + 1] = coef * dx1 * rs;
            cx[(size_t)e * 3 + 2] = coef * dx2 * rs;
        }
    }
}

// ---------------------------------------------------------------------------
// Legacy fp32 edge kernel — kept ONLY as the no-workspace fallback path.
// ---------------------------------------------------------------------------
template <int LAYER>
__global__ __launch_bounds__(256) void edge_kernel_fb(
    const float* __restrict__ h, const float* __restrict__ x,
    const float* __restrict__ ef, const int* __restrict__ src,
    const int* __restrict__ dst,
    const float* __restrict__ ew1, const float* __restrict__ eb1,
    const float* __restrict__ ew2, const float* __restrict__ eb2,
    const float* __restrict__ cw1, const float* __restrict__ cb1,
    const float* __restrict__ cw2,
    float* __restrict__ h_agg, float* __restrict__ x_agg)
{
    __shared__ float fbuf[64 * 65];
    __shared__ int   ridx[64];
    __shared__ float gbuf[256];

    const int tid   = threadIdx.x;
    const int lane  = tid & 63;
    const int wv    = tid >> 6;
    const int J0    = __builtin_amdgcn_readfirstlane(wv * 16);
    const int ebase = blockIdx.x * 64;
    const int e     = ebase + lane;

    const int vs = src[e];
    const int vd = dst[e];

    float dx0 = x[vs * 3 + 0] - x[vd * 3 + 0];
    float dx1 = x[vs * 3 + 1] - x[vd * 3 + 1];
    float dx2 = x[vs * 3 + 2] - x[vd * 3 + 2];
    float radial = dx0 * dx0 + dx1 * dx1 + dx2 * dx2;
    float rs = 1.0f / (sqrtf(radial) + 1e-30f);
    const float4 e4 = *reinterpret_cast<const float4*>(ef + (size_t)e * 4);

    float acc[16];
#pragma unroll
    for (int jj = 0; jj < 16; ++jj) acc[jj] = eb1[J0 + jj];

    if (wv == 0) ridx[lane] = vs;
    __syncthreads();
#pragma unroll
    for (int rr = 0; rr < 16; ++rr) {
        int r = wv * 16 + rr;
        fbuf[r * 65 + lane] = h[(size_t)ridx[r] * 64 + lane];
    }
    __syncthreads();
    for (int i = 0; i < 64; ++i) {
        float fi = fbuf[lane * 65 + i];
#pragma unroll
        for (int jj = 0; jj < 16; ++jj) acc[jj] += fi * ew1[i * 64 + J0 + jj];
    }
    __syncthreads();

    if (wv == 0) ridx[lane] = vd;
    __syncthreads();
#pragma unroll
    for (int rr = 0; rr < 16; ++rr) {
        int r = wv * 16 + rr;
        fbuf[r * 65 + lane] = h[(size_t)ridx[r] * 64 + lane];
    }
    __syncthreads();
    for (int i = 0; i < 64; ++i) {
        float fi = fbuf[lane * 65 + i];
#pragma unroll
        for (int jj = 0; jj < 16; ++jj) acc[jj] += fi * ew1[(64 + i) * 64 + J0 + jj];
    }

#pragma unroll
    for (int jj = 0; jj < 16; ++jj) {
        int j = J0 + jj;
        acc[jj] += radial * ew1[128 * 64 + j] + e4.x * ew1[129 * 64 + j]
                 + e4.y * ew1[130 * 64 + j] + e4.z * ew1[131 * 64 + j]
                 + e4.w * ew1[132 * 64 + j];
    }

    __syncthreads();
#pragma unroll
    for (int jj = 0; jj < 16; ++jj) fbuf[lane * 65 + J0 + jj] = silu_f(acc[jj]);
    __syncthreads();

    float acc2[16];
#pragma unroll
    for (int jj = 0; jj < 16; ++jj) acc2[jj] = eb2[J0 + jj];
    for (int i = 0; i < 64; ++i) {
        float fi = fbuf[lane * 65 + i];
#pragma unroll
        for (int jj = 0; jj < 16; ++jj) acc2[jj] += fi * ew2[i * 64 + J0 + jj];
    }
    __syncthreads();
#pragma unroll
    for (int jj = 0; jj < 16; ++jj) fbuf[lane * 65 + J0 + jj] = silu_f(acc2[jj]);
    __syncthreads();

    if (LAYER == 1) {
        float acc3[16];
#pragma unroll
        for (int jj = 0; jj < 16; ++jj) acc3[jj] = cb1[J0 + jj];
        for (int i = 0; i < 64; ++i) {
            float fi = fbuf[lane * 65 + i];
#pragma unroll
            for (int jj = 0; jj < 16; ++jj) acc3[jj] += fi * cw1[i * 64 + J0 + jj];
        }
        float part = 0.0f;
#pragma unroll
        for (int jj = 0; jj < 16; ++jj) part += silu_f(acc3[jj]) * cw2[J0 + jj];
        gbuf[wv * 64 + lane] = part;
        __syncthreads();
        if (wv == 0) {
            float coef = gbuf[lane] + gbuf[64 + lane] + gbuf[128 + lane] + gbuf[192 + lane];
            atomicAdd(&x_agg[(size_t)vd * 3 + 0], coef * dx0 * rs);
            atomicAdd(&x_agg[(size_t)vd * 3 + 1], coef * dx1 * rs);
            atomicAdd(&x_agg[(size_t)vd * 3 + 2], coef * dx2 * rs);
        }
    }

    float* hrow = h_agg + (size_t)vd * 64;
#pragma unroll
    for (int jj = 0; jj < 16; ++jj)
        atomicAdd(hrow + J0 + jj, fbuf[lane * 65 + J0 + jj]);
}

// ---------------------------------------------------------------------------
// Aggregation: one wave per node, lane = feature.
// ---------------------------------------------------------------------------
template <int LAYER>
__global__ __launch_bounds__(256) void agg_kernel(
    const float* __restrict__ msg,
    const float* __restrict__ cx,
    const int*   __restrict__ eids,
    const int*   __restrict__ starts,
    const int*   __restrict__ cnt,
    float* __restrict__ h_agg,
    float* __restrict__ x_agg)
{
    const int lane = threadIdx.x & 63;
    const int wv   = threadIdx.x >> 6;
    const int node = blockIdx.x * 4 + wv;

    float a  = 0.0f;
    float xa = 0.0f;
    if (node < N_NODES) {
        int s = starts[node];
        int d = cnt[node];
        for (int k = 0; k < d; ++k) {
            int eid = eids[s + k];
            a += msg[(size_t)eid * 64 + lane];
            if (LAYER == 1 && lane < 3) xa += cx[(size_t)eid * 3 + lane];
        }
    }
    h_agg[(size_t)node * 64 + lane] = a;
    if (LAYER == 1 && lane < 3) x_agg[(size_t)node * 3 + lane] = xa;
}

// ---------------------------------------------------------------------------
// Node kernel (unchanged).
// ---------------------------------------------------------------------------
template <int FINAL>
__global__ __launch_bounds__(64) void node_kernel(
    const float* __restrict__ h,
    const float* __restrict__ x,
    const float* __restrict__ h_agg,
    const float* __restrict__ x_agg,
    const float* __restrict__ nw1,
    const float* __restrict__ nb1,
    const float* __restrict__ nw2,
    const float* __restrict__ nb2,
    float* __restrict__ h_out,
    float* __restrict__ x_out)
{
    __shared__ float fbuf[64 * 65];

    const int lane  = threadIdx.x;
    const int nbase = blockIdx.x * 64;
    const int node  = nbase + lane;
    const bool valid = node < N_NODES;

    float acc[64];
#pragma unroll
    for (int j = 0; j < 64; ++j) acc[j] = nb1[j];

#pragma unroll 4
    for (int r = 0; r < 64; ++r) {
        int rr = nbase + r; rr = rr < N_NODES ? rr : (N_NODES - 1);
        fbuf[r * 65 + lane] = h[(size_t)rr * 64 + lane];
    }
    __syncthreads();
    for (int i = 0; i < 64; ++i) {
        float fi = fbuf[lane * 65 + i];
#pragma unroll
        for (int j = 0; j < 64; ++j) acc[j] += fi * nw1[i * 64 + j];
    }
    __syncthreads();

#pragma unroll 4
    for (int r = 0; r < 64; ++r) {
        fbuf[r * 65 + lane] = h_agg[(size_t)(nbase + r) * 64 + lane];
    }
    __syncthreads();
    for (int i = 0; i < 64; ++i) {
        float fi = fbuf[lane * 65 + i];
#pragma unroll
        for (int j = 0; j < 64; ++j) acc[j] += fi * nw1[(64 + i) * 64 + j];
    }
    __syncthreads();

#pragma unroll
    for (int j = 0; j < 64; ++j) fbuf[lane * 65 + j] = silu_f(acc[j]);
    __syncthreads();

    float acc2[64];
#pragma unroll
    for (int j = 0; j < 64; ++j) acc2[j] = nb2[j];
    for (int i = 0; i < 64; ++i) {
        float fi = fbuf[lane * 65 + i];
#pragma unroll
        for (int j = 0; j < 64; ++j) acc2[j] += fi * nw2[i * 64 + j];
    }

    if (FINAL == 0) {
        if (valid) {
#pragma unroll
            for (int j = 0; j < 64; ++j)
                h_out[(size_t)node * 64 + j] = fmaxf(acc2[j], 0.0f);
#pragma unroll
            for (int k = 0; k < 3; ++k)
                x_out[(size_t)node * 3 + k] =
                    fmaxf(x[(size_t)node * 3 + k] + x_agg[(size_t)node * 3 + k], 0.0f);
        }
    } else {
        __syncthreads();
#pragma unroll
        for (int j = 0; j < 64; ++j) fbuf[lane * 65 + j] = valid ? acc2[j] : 0.0f;
        __syncthreads();
        float s = 0.0f;
        for (int r = 0; r < 64; ++r) s += fbuf[r * 65 + lane];
        atomicAdd(&h_out[lane], s);
    }
}

extern "C" void kernel_launch(void* const* d_in, const int* in_sizes, int n_in,
                              void* d_out, int out_size, void* d_ws, size_t ws_size,
                              hipStream_t stream) {
    const float* node_feat = (const float*)d_in[0];
    const float* coord     = (const float*)d_in[1];
    const float* edge_feat = (const float*)d_in[2];
    const int*   src       = (const int*)d_in[3];
    const int*   dst       = (const int*)d_in[4];

    const float* p1[11];
    const float* p2[11];
    for (int i = 0; i < 11; ++i) p1[i] = (const float*)d_in[5 + i];
    for (int i = 0; i < 11; ++i) p2[i] = (const float*)d_in[16 + i];
    // order: ew1 eb1 ew2 eb2 cw1 cb1 cw2 nw1 nb1 nw2 nb2

    float* out = (float*)d_out;

    // workspace layout: floats, then ints, then bf16 weight area
    float* fw    = (float*)d_ws;
    size_t off   = 0;
    float* h_agg = fw + off; off += (size_t)N_PAD * 64;
    float* x_agg = fw + off; off += (size_t)N_PAD * 3;
    float* h1    = fw + off; off += (size_t)N_PAD * 64;
    float* x1    = fw + off; off += (size_t)N_PAD * 3;
    float* msg   = fw + off; off += (size_t)N_EDGES * 64;
    float* cx    = fw + off; off += (size_t)N_EDGES * 3;
    int*   iw    = (int*)(fw + off);
    int*   eids   = iw;
    int*   cnt    = iw + N_EDGES;
    int*   starts = cnt + N_NODES;
    int*   wcur   = starts + N_NODES;
    unsigned short* wbf = (unsigned short*)(wcur + N_NODES);
    unsigned short* wt1_1 = wbf;              // 64*160
    unsigned short* wt1_2 = wbf + 10240;      // 64*160
    unsigned short* wt2_1 = wbf + 20480;      // 64*64
    unsigned short* wt2_2 = wbf + 24576;      // 64*64
    unsigned short* wtc_1 = wbf + 28672;      // 64*64
    size_t need_bytes = off * sizeof(float)
                      + (size_t)(N_EDGES + 3 * N_NODES) * sizeof(int)
                      + 32768 * sizeof(unsigned short);

    const bool use_csr = ws_size >= need_bytes;

    hipMemsetAsync(out, 0, 64 * sizeof(float), stream);

    if (use_csr) {
        // ---- one-time prep: CSR + bf16 weights ----
        hipMemsetAsync(cnt, 0, (size_t)N_NODES * sizeof(int), stream);
        count_kernel<<<(N_EDGES + 255) / 256, 256, 0, stream>>>(dst, cnt);
        scan_kernel<<<1, 1024, 0, stream>>>(cnt, starts, wcur);
        fill_kernel<<<(N_EDGES + 255) / 256, 256, 0, stream>>>(dst, wcur, eids);
        prep_weights<<<(64 * 160 + 64 * 64 + 255) / 256, 256, 0, stream>>>(
            p1[0], p1[2], p1[4], p2[0], p2[2],
            wt1_1, wt2_1, wtc_1, wt1_2, wt2_2);

        // ---- layer 1 ----
        edge_mfma_kernel<1><<<N_EDGES / 64, 256, 0, stream>>>(
            node_feat, coord, edge_feat, src, dst,
            wt1_1, p1[1], wt2_1, p1[3], wtc_1, p1[5], p1[6],
            msg, cx);
        agg_kernel<1><<<N_PAD / 4, 256, 0, stream>>>(
            msg, cx, eids, starts, cnt, h_agg, x_agg);
        node_kernel<0><<<(N_NODES + 63) / 64, 64, 0, stream>>>(
            node_feat, coord, h_agg, x_agg,
            p1[7], p1[8], p1[9], p1[10], h1, x1);

        // ---- layer 2 (gate not needed: x output discarded) ----
        edge_mfma_kernel<2><<<N_EDGES / 64, 256, 0, stream>>>(
            h1, x1, edge_feat, src, dst,
            wt1_2, p2[1], wt2_2, p2[3], wtc_1, p2[5], p2[6],
            msg, cx);
        agg_kernel<2><<<N_PAD / 4, 256, 0, stream>>>(
            msg, cx, eids, starts, cnt, h_agg, x_agg);
        node_kernel<1><<<(N_NODES + 63) / 64, 64, 0, stream>>>(
            h1, x1, h_agg, x_agg,
            p2[7], p2[8], p2[9], p2[10], out, nullptr);
    } else {
        // ---- fallback: atomic scatter path (fp32 GEMV) ----
        hipMemsetAsync(h_agg, 0, (size_t)N_PAD * 64 * sizeof(float), stream);
        hipMemsetAsync(x_agg, 0, (size_t)N_PAD * 3 * sizeof(float), stream);

        edge_kernel_fb<1><<<N_EDGES / 64, 256, 0, stream>>>(
            node_feat, coord, edge_feat, src, dst,
            p1[0], p1[1], p1[2], p1[3], p1[4], p1[5], p1[6],
            h_agg, x_agg);
        node_kernel<0><<<(N_NODES + 63) / 64, 64, 0, stream>>>(
            node_feat, coord, h_agg, x_agg,
            p1[7], p1[8], p1[9], p1[10], h1, x1);

        hipMemsetAsync(h_agg, 0, (size_t)N_PAD * 64 * sizeof(float), stream);
        edge_kernel_fb<2><<<N_EDGES / 64, 256, 0, stream>>>(
            h1, x1, edge_feat, src, dst,
            p2[0], p2[1], p2[2], p2[3], p2[4], p2[5], p2[6],
            h_agg, x_agg);
        node_kernel<1><<<(N_NODES + 63) / 64, 64, 0, stream>>>(
            h1, x1, h_agg, x_agg,
            p2[7], p2[8], p2[9], p2[10], out, nullptr);
    }
}